// Round 1
// baseline (546.585 us; speedup 1.0000x reference)
//
#include <hip/hip_runtime.h>
#include <hip/hip_bf16.h>
#include <math.h>

#define H 128
#define NTPB 256
#define CHUNK 1024  // elements per scan block (256 threads x 4)
#define SRC_MASK 0x1FFFFu
#define WSCALE (1.0f / 32767.0f)

typedef __attribute__((ext_vector_type(8))) short short8;
typedef __attribute__((ext_vector_type(4))) float floatx4;

__device__ __forceinline__ void atomAddF(float* p, float v) {
    __hip_atomic_fetch_add(p, v, __ATOMIC_RELAXED, __HIP_MEMORY_SCOPE_AGENT);
}

__device__ __forceinline__ short f2bf(float v) {
    __hip_bfloat16 b = __float2bfloat16(v);
    return __builtin_bit_cast(short, b);
}

// deg[d] = number of in-edges (1 edge/thread: max waves to hide atomic latency)
__global__ void deg_kernel(const int* __restrict__ ei, int E, int* __restrict__ deg) {
    int e = blockIdx.x * blockDim.x + threadIdx.x;
    if (e < E) atomicAdd(&deg[ei[E + e]], 1);
}

// ---- exclusive scan of deg -> rowptr ----
__global__ void scan_partial(const int* __restrict__ deg, int N, int* __restrict__ partial) {
    __shared__ int sd[NTPB];
    int b = blockIdx.x, t = threadIdx.x;
    int base = b * CHUNK + t * 4;
    int s = 0;
#pragma unroll
    for (int k = 0; k < 4; k++) { int i = base + k; if (i < N) s += deg[i]; }
    sd[t] = s; __syncthreads();
    for (int off = NTPB / 2; off > 0; off >>= 1) {
        if (t < off) sd[t] += sd[t + off];
        __syncthreads();
    }
    if (t == 0) partial[b] = sd[0];
}

// wave-parallel scan of block sums (nb <= 128); also writes rowptr[N] = E
__global__ void scan_tops(const int* __restrict__ partial, int nb,
                          int* __restrict__ pscan, int* __restrict__ rowptr, int N) {
    __shared__ int sd[128];
    int t = threadIdx.x;
    int v = (t < nb) ? partial[t] : 0;
    sd[t] = v; __syncthreads();
    for (int s = 1; s < 128; s <<= 1) {
        int u = (t >= s) ? sd[t - s] : 0;
        __syncthreads();
        sd[t] += u;
        __syncthreads();
    }
    if (t < nb) pscan[t] = sd[t] - v;  // exclusive
    if (t == 0) rowptr[N] = sd[127];
}

// also emits dinv
__global__ void scan_apply(const int* __restrict__ deg, int N, const int* __restrict__ pscan,
                           int* __restrict__ rowptr, int* __restrict__ cursor,
                           float* __restrict__ dinv) {
    __shared__ int sd[NTPB];
    int b = blockIdx.x, t = threadIdx.x;
    int base = b * CHUNK + t * 4;
    int d0 = 0, d1 = 0, d2 = 0, d3 = 0;
    if (base + 0 < N) d0 = deg[base + 0];
    if (base + 1 < N) d1 = deg[base + 1];
    if (base + 2 < N) d2 = deg[base + 2];
    if (base + 3 < N) d3 = deg[base + 3];
    int tsum = d0 + d1 + d2 + d3;
    sd[t] = tsum; __syncthreads();
    for (int s = 1; s < NTPB; s <<= 1) {
        int v = (t >= s) ? sd[t - s] : 0;
        __syncthreads();
        sd[t] += v;
        __syncthreads();
    }
    int p0 = sd[t] - tsum + pscan[b];
    int p1 = p0 + d0, p2 = p1 + d1, p3 = p2 + d2;
    if (base + 0 < N) { rowptr[base + 0] = p0; cursor[base + 0] = p0; dinv[base + 0] = rsqrtf((float)(d0 + 1)); }
    if (base + 1 < N) { rowptr[base + 1] = p1; cursor[base + 1] = p1; dinv[base + 1] = rsqrtf((float)(d1 + 1)); }
    if (base + 2 < N) { rowptr[base + 2] = p2; cursor[base + 2] = p2; dinv[base + 2] = rsqrtf((float)(d2 + 1)); }
    if (base + 3 < N) { rowptr[base + 3] = p3; cursor[base + 3] = p3; dinv[base + 3] = rsqrtf((float)(d3 + 1)); }
}

// bucket-scatter: dst-grouped packed edge = (w*32767)<<17 | src (1 edge/thread)
__global__ void scatter_kernel(const int* __restrict__ ei, int E, const float* __restrict__ dinv,
                               int* __restrict__ cursor, unsigned* __restrict__ csr) {
    int e = blockIdx.x * blockDim.x + threadIdx.x;
    if (e >= E) return;
    int s = ei[e], d = ei[E + e];
    int pos = atomicAdd(&cursor[d], 1);
    float w = dinv[s] * dinv[d];
    csr[pos] = ((unsigned)(w * 32767.0f + 0.5f) << 17) | (unsigned)s;
}

// pre-pack W2 into bf16 B-fragments for mfma_f32_16x16x32_bf16
__global__ void bpack_kernel(const float* __restrict__ W2, __hip_bfloat16* __restrict__ Bp) {
    int idx = blockIdx.x * blockDim.x + threadIdx.x;  // 0..2047
    if (idx >= 2048) return;
    int frag = idx >> 6, lane = idx & 63;
    int nt = frag >> 2, c = frag & 3, quad = lane >> 4, m16 = lane & 15;
#pragma unroll
    for (int jj = 0; jj < 8; jj++) {
        int k = c * 32 + quad * 8 + jj;
        Bp[idx * 8 + jj] = __float2bfloat16(W2[k * H + nt * 16 + m16]);
    }
}

// pad x (N x 3) to 16B-aligned float4 rows so each random gather is ONE dwordx4 / one line
__global__ void padx_kernel(const float* __restrict__ x, float4* __restrict__ x4, int N) {
    int n = blockIdx.x * blockDim.x + threadIdx.x;
    if (n < N) x4[n] = make_float4(x[3 * n], x[3 * n + 1], x[3 * n + 2], 0.f);
}

// layer-1 CSR gather on padded x4 (one float4 load per edge), 4-edge unroll
__global__ void l1_gather(const float4* __restrict__ x4, const float* __restrict__ dinv,
                          const int* __restrict__ rowptr, const unsigned* __restrict__ csr,
                          float4* __restrict__ aggx4, int N) {
    int n = blockIdx.x * blockDim.x + threadIdx.x;
    if (n >= N) return;
    float di = dinv[n], d2 = di * di;
    float4 xs = x4[n];
    float a0 = xs.x * d2, a1 = xs.y * d2, a2 = xs.z * d2;
    int beg = rowptr[n], end = rowptr[n + 1];
    int i = beg;
    for (; i + 4 <= end; i += 4) {
        unsigned c0 = csr[i], c1 = csr[i + 1], c2 = csr[i + 2], c3 = csr[i + 3];
        float4 q0 = x4[c0 & SRC_MASK];
        float4 q1 = x4[c1 & SRC_MASK];
        float4 q2 = x4[c2 & SRC_MASK];
        float4 q3 = x4[c3 & SRC_MASK];
        float w0 = (float)(c0 >> 17) * WSCALE, w1 = (float)(c1 >> 17) * WSCALE;
        float w2 = (float)(c2 >> 17) * WSCALE, w3 = (float)(c3 >> 17) * WSCALE;
        a0 += q0.x * w0 + q1.x * w1 + q2.x * w2 + q3.x * w3;
        a1 += q0.y * w0 + q1.y * w1 + q2.y * w2 + q3.y * w3;
        a2 += q0.z * w0 + q1.z * w1 + q2.z * w2 + q3.z * w3;
    }
    for (; i < end; ++i) {
        unsigned c = csr[i];
        float4 q = x4[c & SRC_MASK];
        float w = (float)(c >> 17) * WSCALE;
        a0 += q.x * w; a1 += q.y * w; a2 += q.z * w;
    }
    aggx4[n] = make_float4(a0, a1, a2, 0.f);
}

// FUSED layer-2 gather: agg1[dst] = sum_e w_e * relu(aggx[src]@W1 + b1) + d2*relu(aggx[dst]@W1+b1)
// Exploits linearity of GCNConv: (sum w_e h1[src]) @ W2 == sum w_e (h1@W2)[src].
// Random read per edge is now ONE 16B float4 (vs 256B row before); h1 recomputed
// on the fly (3 fma per output dim, ~8us of VALU device-wide). 16 lanes/node,
// lane owns 8 dims with W1 columns held in registers.
__global__ __launch_bounds__(NTPB, 6) void l2_gather(
        const float4* __restrict__ aggx4, const float* __restrict__ dinv,
        const int* __restrict__ rowptr, const unsigned* __restrict__ csr,
        const float* __restrict__ W1, const float* __restrict__ b1,
        __hip_bfloat16* __restrict__ agg1, int N) {
    int t = threadIdx.x;
    int l16 = t & 15;
    int node = blockIdx.x * 16 + (t >> 4);
    float wa[8], wb[8], wcc[8], bb[8];
#pragma unroll
    for (int j = 0; j < 8; j++) {
        int k = 8 * l16 + j;
        wa[j] = W1[k]; wb[j] = W1[H + k]; wcc[j] = W1[2 * H + k]; bb[j] = b1[k];
    }
    if (node >= N) return;
    float acc[8];
#pragma unroll
    for (int j = 0; j < 8; j++) acc[j] = 0.f;
    int beg = rowptr[node], end = rowptr[node + 1];
    for (int i = beg; i < end; i += 4) {
        int rem = end - i;
        unsigned c0 = csr[i];
        unsigned c1 = (rem > 1) ? csr[i + 1] : 0u;
        unsigned c2 = (rem > 2) ? csr[i + 2] : 0u;
        unsigned c3 = (rem > 3) ? csr[i + 3] : 0u;
        float4 p0 = aggx4[c0 & SRC_MASK];
        float4 p1 = aggx4[c1 & SRC_MASK];
        float4 p2 = aggx4[c2 & SRC_MASK];
        float4 p3 = aggx4[c3 & SRC_MASK];
        float w0 = (float)(c0 >> 17) * WSCALE;
        float w1 = (float)(c1 >> 17) * WSCALE;
        float w2 = (float)(c2 >> 17) * WSCALE;
        float w3 = (float)(c3 >> 17) * WSCALE;
#pragma unroll
        for (int j = 0; j < 8; j++) {
            acc[j] += w0 * fmaxf(p0.x * wa[j] + p0.y * wb[j] + p0.z * wcc[j] + bb[j], 0.f);
            acc[j] += w1 * fmaxf(p1.x * wa[j] + p1.y * wb[j] + p1.z * wcc[j] + bb[j], 0.f);
            acc[j] += w2 * fmaxf(p2.x * wa[j] + p2.y * wb[j] + p2.z * wcc[j] + bb[j], 0.f);
            acc[j] += w3 * fmaxf(p3.x * wa[j] + p3.y * wb[j] + p3.z * wcc[j] + bb[j], 0.f);
        }
    }
    // self-loop contribution (h1 of own node, weight dinv^2)
    float di = dinv[node];
    float d2 = di * di;
    float4 ps = aggx4[node];
#pragma unroll
    for (int j = 0; j < 8; j++)
        acc[j] += d2 * fmaxf(ps.x * wa[j] + ps.y * wb[j] + ps.z * wcc[j] + bb[j], 0.f);
    short8 o;
#pragma unroll
    for (int j = 0; j < 8; j++) o[j] = f2bf(acc[j]);
    *(short8*)(&agg1[(size_t)node * H + 8 * l16]) = o;
}

// Final MFMA: h2 = relu(agg1 @ W2 + b2); dot with Wc; atomic pool by graph.
// Same proven 16-row tile / B-frag layout as the old gemm2_mfma, with a
// dot-product epilogue instead of a row store.
__global__ __launch_bounds__(NTPB, 4) void gemm_pool(
        const __hip_bfloat16* __restrict__ agg1, const __hip_bfloat16* __restrict__ Bp,
        const float* __restrict__ b2, const float* __restrict__ Wc,
        const int* __restrict__ batch,
        float* __restrict__ gsum, int* __restrict__ gcnt, int N) {
    __shared__ float sb2[H];
    __shared__ float swc[H];
    int t = threadIdx.x;
    if (t < H) { sb2[t] = b2[t]; swc[t] = Wc[t]; }
    __syncthreads();
    int wave = t >> 6, lane = t & 63;
    int quad = lane >> 4, m16 = lane & 15;
    int tile = blockIdx.x * 4 + wave;
    int rowbase = tile * 16;
    if (rowbase >= N) return;
    int m = rowbase + m16;
    const short8* as8 = (const short8*)agg1;
    short8 af[4];
    if (m < N) {
#pragma unroll
        for (int c = 0; c < 4; c++) af[c] = as8[(size_t)m * 16 + c * 4 + quad];
    } else {
#pragma unroll
        for (int c = 0; c < 4; c++) af[c] = (short8){0, 0, 0, 0, 0, 0, 0, 0};
    }
    const short8* bp = (const short8*)Bp;
    floatx4 acc[8];
#pragma unroll
    for (int nt = 0; nt < 8; nt++) acc[nt] = (floatx4){0.f, 0.f, 0.f, 0.f};
#pragma unroll
    for (int nt = 0; nt < 8; nt++) {
#pragma unroll
        for (int c = 0; c < 4; c++) {
            short8 bf = bp[(nt * 4 + c) * 64 + lane];
            acc[nt] = __builtin_amdgcn_mfma_f32_16x16x32_bf16(af[c], bf, acc[nt], 0, 0, 0);
        }
    }
    // acc[nt][reg] = D[row = rowbase + quad*4 + reg][col = nt*16 + m16]
    float dot0 = 0.f, dot1 = 0.f, dot2 = 0.f, dot3 = 0.f;
#pragma unroll
    for (int nt = 0; nt < 8; nt++) {
        int col = nt * 16 + m16;
        float bcol = sb2[col], wcol = swc[col];
        dot0 += fmaxf(acc[nt][0] + bcol, 0.f) * wcol;
        dot1 += fmaxf(acc[nt][1] + bcol, 0.f) * wcol;
        dot2 += fmaxf(acc[nt][2] + bcol, 0.f) * wcol;
        dot3 += fmaxf(acc[nt][3] + bcol, 0.f) * wcol;
    }
    // reduce each row-dot across the 16 m16 lanes (same quad => lanes quad*16..quad*16+15)
#pragma unroll
    for (int s = 1; s < 16; s <<= 1) {
        dot0 += __shfl_xor(dot0, s);
        dot1 += __shfl_xor(dot1, s);
        dot2 += __shfl_xor(dot2, s);
        dot3 += __shfl_xor(dot3, s);
    }
    if (m16 < 4) {
        int row = rowbase + quad * 4 + m16;
        if (row < N) {
            float d = (m16 == 0) ? dot0 : (m16 == 1) ? dot1 : (m16 == 2) ? dot2 : dot3;
            int gidx = batch[row];
            atomAddF(&gsum[gidx], d);
            atomicAdd(&gcnt[gidx], 1);
        }
    }
}

__global__ void out_kernel(const float* __restrict__ gsum, const int* __restrict__ gcnt,
                           const float* __restrict__ bc, float* __restrict__ out, int G) {
    int g = blockIdx.x * blockDim.x + threadIdx.x;
    if (g >= G) return;
    float c = fmaxf((float)gcnt[g], 1.f);
    float logit = gsum[g] / c + bc[0];
    out[g] = 1.f / (1.f + expf(-logit));
}

extern "C" void kernel_launch(void* const* d_in, const int* in_sizes, int n_in,
                              void* d_out, int out_size, void* d_ws, size_t ws_size,
                              hipStream_t stream) {
    const float* x     = (const float*)d_in[0];
    const int*   ei    = (const int*)d_in[1];
    const int*   batch = (const int*)d_in[2];
    const float* W1    = (const float*)d_in[3];
    const float* b1    = (const float*)d_in[4];
    const float* W2    = (const float*)d_in[5];
    const float* b2    = (const float*)d_in[6];
    const float* Wc    = (const float*)d_in[7];
    const float* bc    = (const float*)d_in[8];
    float* out = (float*)d_out;

    int N = in_sizes[2];
    int E = in_sizes[1] / 2;
    int G = out_size;
    int NB = (N + CHUNK - 1) / CHUNK;

    char* ws = (char*)d_ws;
    size_t off = 0;
    auto alloc = [&](size_t bytes) {
        void* p = ws + off;
        off += (bytes + 255) & ~(size_t)255;
        return p;
    };
    __hip_bfloat16* agg1 = (__hip_bfloat16*)alloc((size_t)N * H * sizeof(__hip_bfloat16));
    float4* x4    = (float4*)alloc((size_t)N * sizeof(float4));
    float4* aggx4 = (float4*)alloc((size_t)N * sizeof(float4));
    // deg/gsum/gcnt contiguous -> single memset
    int*   deg    = (int*)  alloc((size_t)N * sizeof(int));
    float* gsum   = (float*)alloc((size_t)G * sizeof(float));
    int*   gcnt   = (int*)  alloc((size_t)G * sizeof(int));
    char*  zero_end = ws + off;
    int*   rowptr = (int*)  alloc((size_t)(N + 1) * sizeof(int));
    int*   cursor = (int*)  alloc((size_t)N * sizeof(int));
    float* dinv   = (float*)alloc((size_t)N * sizeof(float));
    unsigned* csr = (unsigned*)alloc((size_t)E * sizeof(unsigned));
    __hip_bfloat16* Bp = (__hip_bfloat16*)alloc((size_t)H * H * sizeof(__hip_bfloat16));
    int*   partial= (int*)  alloc((size_t)NB * sizeof(int));
    int*   pscan  = (int*)  alloc((size_t)NB * sizeof(int));

    (void)hipMemsetAsync(deg, 0, (size_t)(zero_end - (char*)deg), stream);

    deg_kernel<<<(E + NTPB - 1) / NTPB, NTPB, 0, stream>>>(ei, E, deg);

    scan_partial<<<NB, NTPB, 0, stream>>>(deg, N, partial);
    scan_tops<<<1, 128, 0, stream>>>(partial, NB, pscan, rowptr, N);
    scan_apply<<<NB, NTPB, 0, stream>>>(deg, N, pscan, rowptr, cursor, dinv);

    scatter_kernel<<<(E + NTPB - 1) / NTPB, NTPB, 0, stream>>>(ei, E, dinv, cursor, csr);

    bpack_kernel<<<8, NTPB, 0, stream>>>(W2, Bp);
    padx_kernel<<<(N + NTPB - 1) / NTPB, NTPB, 0, stream>>>(x, x4, N);

    l1_gather<<<(N + NTPB - 1) / NTPB, NTPB, 0, stream>>>(x4, dinv, rowptr, csr, aggx4, N);

    l2_gather<<<(N + 15) / 16, NTPB, 0, stream>>>(aggx4, dinv, rowptr, csr, W1, b1, agg1, N);

    {
        int ntiles = (N + 15) / 16;
        gemm_pool<<<(ntiles + 3) / 4, NTPB, 0, stream>>>(agg1, Bp, b2, Wc, batch, gsum, gcnt, N);
    }

    out_kernel<<<(G + NTPB - 1) / NTPB, NTPB, 0, stream>>>(gsum, gcnt, bc, out, G);
}

// Round 2
// 323.833 us; speedup vs baseline: 1.6879x; 1.6879x over previous
//
#include <hip/hip_runtime.h>
#include <hip/hip_bf16.h>
#include <math.h>

#define H 128
#define NTPB 256
#define CHUNK 1024  // elements per scan block (256 threads x 4)
#define SRC_MASK 0x1FFFFu
#define WSCALE (1.0f / 32767.0f)
#define POOL_CHUNK 2048

typedef __attribute__((ext_vector_type(8))) short short8;
typedef __attribute__((ext_vector_type(4))) float floatx4;

__device__ __forceinline__ void atomAddF(float* p, float v) {
    __hip_atomic_fetch_add(p, v, __ATOMIC_RELAXED, __HIP_MEMORY_SCOPE_AGENT);
}

__device__ __forceinline__ short f2bf(float v) {
    __hip_bfloat16 b = __float2bfloat16(v);
    return __builtin_bit_cast(short, b);
}

// deg[d] = number of in-edges (1 edge/thread: max waves to hide atomic latency)
__global__ void deg_kernel(const int* __restrict__ ei, int E, int* __restrict__ deg) {
    int e = blockIdx.x * blockDim.x + threadIdx.x;
    if (e < E) atomicAdd(&deg[ei[E + e]], 1);
}

// ---- exclusive scan of deg -> rowptr ----
__global__ void scan_partial(const int* __restrict__ deg, int N, int* __restrict__ partial) {
    __shared__ int sd[NTPB];
    int b = blockIdx.x, t = threadIdx.x;
    int base = b * CHUNK + t * 4;
    int s = 0;
#pragma unroll
    for (int k = 0; k < 4; k++) { int i = base + k; if (i < N) s += deg[i]; }
    sd[t] = s; __syncthreads();
    for (int off = NTPB / 2; off > 0; off >>= 1) {
        if (t < off) sd[t] += sd[t + off];
        __syncthreads();
    }
    if (t == 0) partial[b] = sd[0];
}

// wave-parallel scan of block sums (nb <= 128); also writes rowptr[N] = E
__global__ void scan_tops(const int* __restrict__ partial, int nb,
                          int* __restrict__ pscan, int* __restrict__ rowptr, int N) {
    __shared__ int sd[128];
    int t = threadIdx.x;
    int v = (t < nb) ? partial[t] : 0;
    sd[t] = v; __syncthreads();
    for (int s = 1; s < 128; s <<= 1) {
        int u = (t >= s) ? sd[t - s] : 0;
        __syncthreads();
        sd[t] += u;
        __syncthreads();
    }
    if (t < nb) pscan[t] = sd[t] - v;  // exclusive
    if (t == 0) rowptr[N] = sd[127];
}

// also emits dinv
__global__ void scan_apply(const int* __restrict__ deg, int N, const int* __restrict__ pscan,
                           int* __restrict__ rowptr, int* __restrict__ cursor,
                           float* __restrict__ dinv) {
    __shared__ int sd[NTPB];
    int b = blockIdx.x, t = threadIdx.x;
    int base = b * CHUNK + t * 4;
    int d0 = 0, d1 = 0, d2 = 0, d3 = 0;
    if (base + 0 < N) d0 = deg[base + 0];
    if (base + 1 < N) d1 = deg[base + 1];
    if (base + 2 < N) d2 = deg[base + 2];
    if (base + 3 < N) d3 = deg[base + 3];
    int tsum = d0 + d1 + d2 + d3;
    sd[t] = tsum; __syncthreads();
    for (int s = 1; s < NTPB; s <<= 1) {
        int v = (t >= s) ? sd[t - s] : 0;
        __syncthreads();
        sd[t] += v;
        __syncthreads();
    }
    int p0 = sd[t] - tsum + pscan[b];
    int p1 = p0 + d0, p2 = p1 + d1, p3 = p2 + d2;
    if (base + 0 < N) { rowptr[base + 0] = p0; cursor[base + 0] = p0; dinv[base + 0] = rsqrtf((float)(d0 + 1)); }
    if (base + 1 < N) { rowptr[base + 1] = p1; cursor[base + 1] = p1; dinv[base + 1] = rsqrtf((float)(d1 + 1)); }
    if (base + 2 < N) { rowptr[base + 2] = p2; cursor[base + 2] = p2; dinv[base + 2] = rsqrtf((float)(d2 + 1)); }
    if (base + 3 < N) { rowptr[base + 3] = p3; cursor[base + 3] = p3; dinv[base + 3] = rsqrtf((float)(d3 + 1)); }
}

// bucket-scatter: dst-grouped packed edge = (w*32767)<<17 | src (1 edge/thread)
__global__ void scatter_kernel(const int* __restrict__ ei, int E, const float* __restrict__ dinv,
                               int* __restrict__ cursor, unsigned* __restrict__ csr) {
    int e = blockIdx.x * blockDim.x + threadIdx.x;
    if (e >= E) return;
    int s = ei[e], d = ei[E + e];
    int pos = atomicAdd(&cursor[d], 1);
    float w = dinv[s] * dinv[d];
    csr[pos] = ((unsigned)(w * 32767.0f + 0.5f) << 17) | (unsigned)s;
}

// pre-pack W2 into bf16 B-fragments for mfma_f32_16x16x32_bf16
__global__ void bpack_kernel(const float* __restrict__ W2, __hip_bfloat16* __restrict__ Bp) {
    int idx = blockIdx.x * blockDim.x + threadIdx.x;  // 0..2047
    if (idx >= 2048) return;
    int frag = idx >> 6, lane = idx & 63;
    int nt = frag >> 2, c = frag & 3, quad = lane >> 4, m16 = lane & 15;
#pragma unroll
    for (int jj = 0; jj < 8; jj++) {
        int k = c * 32 + quad * 8 + jj;
        Bp[idx * 8 + jj] = __float2bfloat16(W2[k * H + nt * 16 + m16]);
    }
}

// pad x (N x 3) to 16B-aligned float4 rows so each random gather is ONE dwordx4 / one line
__global__ void padx_kernel(const float* __restrict__ x, float4* __restrict__ x4, int N) {
    int n = blockIdx.x * blockDim.x + threadIdx.x;
    if (n < N) x4[n] = make_float4(x[3 * n], x[3 * n + 1], x[3 * n + 2], 0.f);
}

// layer-1 CSR gather on padded x4 (one float4 load per edge), 4-edge unroll
__global__ void l1_gather(const float4* __restrict__ x4, const float* __restrict__ dinv,
                          const int* __restrict__ rowptr, const unsigned* __restrict__ csr,
                          float4* __restrict__ aggx4, int N) {
    int n = blockIdx.x * blockDim.x + threadIdx.x;
    if (n >= N) return;
    float di = dinv[n], d2 = di * di;
    float4 xs = x4[n];
    float a0 = xs.x * d2, a1 = xs.y * d2, a2 = xs.z * d2;
    int beg = rowptr[n], end = rowptr[n + 1];
    int i = beg;
    for (; i + 4 <= end; i += 4) {
        unsigned c0 = csr[i], c1 = csr[i + 1], c2 = csr[i + 2], c3 = csr[i + 3];
        float4 q0 = x4[c0 & SRC_MASK];
        float4 q1 = x4[c1 & SRC_MASK];
        float4 q2 = x4[c2 & SRC_MASK];
        float4 q3 = x4[c3 & SRC_MASK];
        float w0 = (float)(c0 >> 17) * WSCALE, w1 = (float)(c1 >> 17) * WSCALE;
        float w2 = (float)(c2 >> 17) * WSCALE, w3 = (float)(c3 >> 17) * WSCALE;
        a0 += q0.x * w0 + q1.x * w1 + q2.x * w2 + q3.x * w3;
        a1 += q0.y * w0 + q1.y * w1 + q2.y * w2 + q3.y * w3;
        a2 += q0.z * w0 + q1.z * w1 + q2.z * w2 + q3.z * w3;
    }
    for (; i < end; ++i) {
        unsigned c = csr[i];
        float4 q = x4[c & SRC_MASK];
        float w = (float)(c >> 17) * WSCALE;
        a0 += q.x * w; a1 += q.y * w; a2 += q.z * w;
    }
    aggx4[n] = make_float4(a0, a1, a2, 0.f);
}

// FUSED layer-2 gather: agg1[dst] = sum_e w_e * relu(aggx[src]@W1 + b1) + d2*relu(aggx[dst]@W1+b1)
// Random read per edge is ONE 16B float4 (aggx4 is 1.6MB -> L2-resident);
// h1 recomputed on the fly. 16 lanes/node, lane owns 8 dims, W1 cols in regs.
// NO launch_bounds: the (256,6) cap forced a VGPR spill (WRITE_SIZE 352MB of
// scratch, dur 154us); unconstrained allocator keeps the ~70 live values in regs.
__global__ void l2_gather(
        const float4* __restrict__ aggx4, const float* __restrict__ dinv,
        const int* __restrict__ rowptr, const unsigned* __restrict__ csr,
        const float* __restrict__ W1, const float* __restrict__ b1,
        __hip_bfloat16* __restrict__ agg1, int N) {
    int t = threadIdx.x;
    int l16 = t & 15;
    int node = blockIdx.x * 16 + (t >> 4);
    float wa[8], wb[8], wcc[8], bb[8];
#pragma unroll
    for (int j = 0; j < 8; j++) {
        int k = 8 * l16 + j;
        wa[j] = W1[k]; wb[j] = W1[H + k]; wcc[j] = W1[2 * H + k]; bb[j] = b1[k];
    }
    if (node >= N) return;
    float acc[8];
#pragma unroll
    for (int j = 0; j < 8; j++) acc[j] = 0.f;
    int beg = rowptr[node], end = rowptr[node + 1];
    for (int i = beg; i < end; i += 4) {
        int rem = end - i;
        unsigned c0 = csr[i];
        unsigned c1 = (rem > 1) ? csr[i + 1] : 0u;
        unsigned c2 = (rem > 2) ? csr[i + 2] : 0u;
        unsigned c3 = (rem > 3) ? csr[i + 3] : 0u;
        float4 p0 = aggx4[c0 & SRC_MASK];
        float4 p1 = aggx4[c1 & SRC_MASK];
        float4 p2 = aggx4[c2 & SRC_MASK];
        float4 p3 = aggx4[c3 & SRC_MASK];
        float w0 = (float)(c0 >> 17) * WSCALE;
        float w1 = (float)(c1 >> 17) * WSCALE;
        float w2 = (float)(c2 >> 17) * WSCALE;
        float w3 = (float)(c3 >> 17) * WSCALE;
#pragma unroll
        for (int j = 0; j < 8; j++) {
            acc[j] += w0 * fmaxf(p0.x * wa[j] + p0.y * wb[j] + p0.z * wcc[j] + bb[j], 0.f);
            acc[j] += w1 * fmaxf(p1.x * wa[j] + p1.y * wb[j] + p1.z * wcc[j] + bb[j], 0.f);
            acc[j] += w2 * fmaxf(p2.x * wa[j] + p2.y * wb[j] + p2.z * wcc[j] + bb[j], 0.f);
            acc[j] += w3 * fmaxf(p3.x * wa[j] + p3.y * wb[j] + p3.z * wcc[j] + bb[j], 0.f);
        }
    }
    // self-loop contribution (h1 of own node, weight dinv^2)
    float di = dinv[node];
    float d2 = di * di;
    float4 ps = aggx4[node];
#pragma unroll
    for (int j = 0; j < 8; j++)
        acc[j] += d2 * fmaxf(ps.x * wa[j] + ps.y * wb[j] + ps.z * wcc[j] + bb[j], 0.f);
    short8 o;
#pragma unroll
    for (int j = 0; j < 8; j++) o[j] = f2bf(acc[j]);
    *(short8*)(&agg1[(size_t)node * H + 8 * l16]) = o;
}

// Final MFMA: h2 = relu(agg1 @ W2 + b2); dot with Wc -> nodedot[row].
// NO atomics here: the 200k contended gsum/gcnt atomics (sorted batch => same-
// address clustering) were the entire 155us duration of the previous version.
__global__ __launch_bounds__(NTPB, 4) void gemm_nodedot(
        const __hip_bfloat16* __restrict__ agg1, const __hip_bfloat16* __restrict__ Bp,
        const float* __restrict__ b2, const float* __restrict__ Wc,
        float* __restrict__ nodedot, int N) {
    __shared__ float sb2[H];
    __shared__ float swc[H];
    int t = threadIdx.x;
    if (t < H) { sb2[t] = b2[t]; swc[t] = Wc[t]; }
    __syncthreads();
    int wave = t >> 6, lane = t & 63;
    int quad = lane >> 4, m16 = lane & 15;
    int tile = blockIdx.x * 4 + wave;
    int rowbase = tile * 16;
    if (rowbase >= N) return;
    int m = rowbase + m16;
    const short8* as8 = (const short8*)agg1;
    short8 af[4];
    if (m < N) {
#pragma unroll
        for (int c = 0; c < 4; c++) af[c] = as8[(size_t)m * 16 + c * 4 + quad];
    } else {
#pragma unroll
        for (int c = 0; c < 4; c++) af[c] = (short8){0, 0, 0, 0, 0, 0, 0, 0};
    }
    const short8* bp = (const short8*)Bp;
    floatx4 acc[8];
#pragma unroll
    for (int nt = 0; nt < 8; nt++) acc[nt] = (floatx4){0.f, 0.f, 0.f, 0.f};
#pragma unroll
    for (int nt = 0; nt < 8; nt++) {
#pragma unroll
        for (int c = 0; c < 4; c++) {
            short8 bf = bp[(nt * 4 + c) * 64 + lane];
            acc[nt] = __builtin_amdgcn_mfma_f32_16x16x32_bf16(af[c], bf, acc[nt], 0, 0, 0);
        }
    }
    // acc[nt][reg] = D[row = rowbase + quad*4 + reg][col = nt*16 + m16]
    float dot0 = 0.f, dot1 = 0.f, dot2 = 0.f, dot3 = 0.f;
#pragma unroll
    for (int nt = 0; nt < 8; nt++) {
        int col = nt * 16 + m16;
        float bcol = sb2[col], wcol = swc[col];
        dot0 += fmaxf(acc[nt][0] + bcol, 0.f) * wcol;
        dot1 += fmaxf(acc[nt][1] + bcol, 0.f) * wcol;
        dot2 += fmaxf(acc[nt][2] + bcol, 0.f) * wcol;
        dot3 += fmaxf(acc[nt][3] + bcol, 0.f) * wcol;
    }
    // reduce each row-dot across the 16 m16 lanes of this quad-group
#pragma unroll
    for (int s = 1; s < 16; s <<= 1) {
        dot0 += __shfl_xor(dot0, s);
        dot1 += __shfl_xor(dot1, s);
        dot2 += __shfl_xor(dot2, s);
        dot3 += __shfl_xor(dot3, s);
    }
    if (m16 < 4) {
        int row = rowbase + quad * 4 + m16;
        if (row < N) {
            float d = (m16 == 0) ? dot0 : (m16 == 1) ? dot1 : (m16 == 2) ? dot2 : dot3;
            nodedot[row] = d;
        }
    }
}

// segmented mean-pool: batch is SORTED, so each 2048-node chunk spans ~12 graphs.
// LDS-privatized accumulation, then ~12 global atomics per block (~600 total,
// vs 200k contended before).
__global__ void pool_kernel(const float* __restrict__ nodedot, const int* __restrict__ batch,
                            float* __restrict__ gsum, int* __restrict__ gcnt, int N, int G) {
    extern __shared__ char sm[];
    float* ls = (float*)sm;            // G floats
    int*   lc = (int*)(sm + (size_t)G * sizeof(float));  // G ints
    int t = threadIdx.x;
    for (int g = t; g < G; g += blockDim.x) { ls[g] = 0.f; lc[g] = 0; }
    __syncthreads();
    int base = blockIdx.x * POOL_CHUNK;
    int endn = min(base + POOL_CHUNK, N);
    for (int n = base + t; n < endn; n += blockDim.x) {
        int g = batch[n];
        atomicAdd(&ls[g], nodedot[n]);
        atomicAdd(&lc[g], 1);
    }
    __syncthreads();
    for (int g = t; g < G; g += blockDim.x) {
        if (lc[g] != 0) {
            atomAddF(&gsum[g], ls[g]);
            atomicAdd(&gcnt[g], lc[g]);
        }
    }
}

__global__ void out_kernel(const float* __restrict__ gsum, const int* __restrict__ gcnt,
                           const float* __restrict__ bc, float* __restrict__ out, int G) {
    int g = blockIdx.x * blockDim.x + threadIdx.x;
    if (g >= G) return;
    float c = fmaxf((float)gcnt[g], 1.f);
    float logit = gsum[g] / c + bc[0];
    out[g] = 1.f / (1.f + expf(-logit));
}

extern "C" void kernel_launch(void* const* d_in, const int* in_sizes, int n_in,
                              void* d_out, int out_size, void* d_ws, size_t ws_size,
                              hipStream_t stream) {
    const float* x     = (const float*)d_in[0];
    const int*   ei    = (const int*)d_in[1];
    const int*   batch = (const int*)d_in[2];
    const float* W1    = (const float*)d_in[3];
    const float* b1    = (const float*)d_in[4];
    const float* W2    = (const float*)d_in[5];
    const float* b2    = (const float*)d_in[6];
    const float* Wc    = (const float*)d_in[7];
    const float* bc    = (const float*)d_in[8];
    float* out = (float*)d_out;

    int N = in_sizes[2];
    int E = in_sizes[1] / 2;
    int G = out_size;
    int NB = (N + CHUNK - 1) / CHUNK;

    char* ws = (char*)d_ws;
    size_t off = 0;
    auto alloc = [&](size_t bytes) {
        void* p = ws + off;
        off += (bytes + 255) & ~(size_t)255;
        return p;
    };
    __hip_bfloat16* agg1 = (__hip_bfloat16*)alloc((size_t)N * H * sizeof(__hip_bfloat16));
    float4* x4    = (float4*)alloc((size_t)N * sizeof(float4));
    float4* aggx4 = (float4*)alloc((size_t)N * sizeof(float4));
    float* nodedot= (float*)alloc((size_t)N * sizeof(float));
    // deg/gsum/gcnt contiguous -> single memset
    int*   deg    = (int*)  alloc((size_t)N * sizeof(int));
    float* gsum   = (float*)alloc((size_t)G * sizeof(float));
    int*   gcnt   = (int*)  alloc((size_t)G * sizeof(int));
    char*  zero_end = ws + off;
    int*   rowptr = (int*)  alloc((size_t)(N + 1) * sizeof(int));
    int*   cursor = (int*)  alloc((size_t)N * sizeof(int));
    float* dinv   = (float*)alloc((size_t)N * sizeof(float));
    unsigned* csr = (unsigned*)alloc((size_t)E * sizeof(unsigned));
    __hip_bfloat16* Bp = (__hip_bfloat16*)alloc((size_t)H * H * sizeof(__hip_bfloat16));
    int*   partial= (int*)  alloc((size_t)NB * sizeof(int));
    int*   pscan  = (int*)  alloc((size_t)NB * sizeof(int));

    (void)hipMemsetAsync(deg, 0, (size_t)(zero_end - (char*)deg), stream);

    deg_kernel<<<(E + NTPB - 1) / NTPB, NTPB, 0, stream>>>(ei, E, deg);

    scan_partial<<<NB, NTPB, 0, stream>>>(deg, N, partial);
    scan_tops<<<1, 128, 0, stream>>>(partial, NB, pscan, rowptr, N);
    scan_apply<<<NB, NTPB, 0, stream>>>(deg, N, pscan, rowptr, cursor, dinv);

    scatter_kernel<<<(E + NTPB - 1) / NTPB, NTPB, 0, stream>>>(ei, E, dinv, cursor, csr);

    bpack_kernel<<<8, NTPB, 0, stream>>>(W2, Bp);
    padx_kernel<<<(N + NTPB - 1) / NTPB, NTPB, 0, stream>>>(x, x4, N);

    l1_gather<<<(N + NTPB - 1) / NTPB, NTPB, 0, stream>>>(x4, dinv, rowptr, csr, aggx4, N);

    l2_gather<<<(N + 15) / 16, NTPB, 0, stream>>>(aggx4, dinv, rowptr, csr, W1, b1, agg1, N);

    {
        int ntiles = (N + 15) / 16;
        gemm_nodedot<<<(ntiles + 3) / 4, NTPB, 0, stream>>>(agg1, Bp, b2, Wc, nodedot, N);
    }

    {
        int pblocks = (N + POOL_CHUNK - 1) / POOL_CHUNK;
        size_t smem = (size_t)G * (sizeof(float) + sizeof(int));
        pool_kernel<<<pblocks, NTPB, smem, stream>>>(nodedot, batch, gsum, gcnt, N, G);
    }

    out_kernel<<<(G + NTPB - 1) / NTPB, NTPB, 0, stream>>>(gsum, gcnt, bc, out, G);
}

// Round 3
// 246.725 us; speedup vs baseline: 2.2154x; 1.3125x over previous
//
#include <hip/hip_runtime.h>
#include <hip/hip_bf16.h>
#include <math.h>

#define H 128
#define NTPB 256
#define NBKT 256      // dst buckets, 512 nodes each
#define BSH 9
#define BMSK 511
#define EPB 8192      // edges per partition/hist block
#define POOL_CHUNK 2048

typedef __attribute__((ext_vector_type(8))) short short8;
typedef __attribute__((ext_vector_type(4))) float floatx4;

__device__ __forceinline__ void atomAddF(float* p, float v) {
    __hip_atomic_fetch_add(p, v, __ATOMIC_RELAXED, __HIP_MEMORY_SCOPE_AGENT);
}

__device__ __forceinline__ short f2bf(float v) {
    __hip_bfloat16 b = __float2bfloat16(v);
    return __builtin_bit_cast(short, b);
}

// ---- CSR build, pass 1: per-bucket edge histogram (bucket = dst>>9) ----
__global__ void hist_kernel(const int* __restrict__ ei, int E, int* __restrict__ ghist) {
    __shared__ int lh[NBKT];
    int t = threadIdx.x;
    lh[t] = 0;
    __syncthreads();
    int base = blockIdx.x * EPB;
#pragma unroll
    for (int k = 0; k < EPB / NTPB; k++) {
        int e = base + k * NTPB + t;
        if (e < E) atomicAdd(&lh[((unsigned)ei[E + e]) >> BSH], 1);
    }
    __syncthreads();
    if (lh[t]) atomicAdd(&ghist[t], lh[t]);
}

// ---- pass 2: scan bucket counts -> gbase[257]; init gcursor ----
__global__ void scan_buckets(const int* __restrict__ ghist, int* __restrict__ gbase,
                             int* __restrict__ gcursor) {
    __shared__ int sd[NBKT];
    int t = threadIdx.x;
    int v = ghist[t];
    sd[t] = v; __syncthreads();
    for (int s = 1; s < NBKT; s <<= 1) {
        int u = (t >= s) ? sd[t - s] : 0;
        __syncthreads();
        sd[t] += u;
        __syncthreads();
    }
    int ex = sd[t] - v;
    gbase[t] = ex;
    gcursor[t] = ex;
    if (t == NBKT - 1) gbase[NBKT] = sd[t];
}

// ---- pass 3: partition edges into bucket-contiguous ebuf ----
// Per block: LDS ranks (1.6M LDS atomics, cheap), ONE global atomic per bucket
// per block (50k total on 256 addrs), then writes in ~128B runs per bucket.
// Replaces the 1.6M random 4B stores (107MB of line-allocated HBM writes).
__global__ void partition_kernel(const int* __restrict__ ei, int E,
                                 int* __restrict__ gcursor, unsigned* __restrict__ ebuf) {
    __shared__ int lcur[NBKT];
    __shared__ int lbase[NBKT];
    int t = threadIdx.x;
    lcur[t] = 0;
    __syncthreads();
    int base = blockIdx.x * EPB;
    unsigned short rk[EPB / NTPB];
#pragma unroll
    for (int k = 0; k < EPB / NTPB; k++) {
        int e = base + k * NTPB + t;
        rk[k] = 0;
        if (e < E) rk[k] = (unsigned short)atomicAdd(&lcur[((unsigned)ei[E + e]) >> BSH], 1);
    }
    __syncthreads();
    lbase[t] = atomicAdd(&gcursor[t], lcur[t]);
    __syncthreads();
#pragma unroll
    for (int k = 0; k < EPB / NTPB; k++) {
        int e = base + k * NTPB + t;
        if (e < E) {
            unsigned d = (unsigned)ei[E + e];
            unsigned s = (unsigned)ei[e];
            ebuf[lbase[d >> BSH] + rk[k]] = ((d & BMSK) << 17) | s;
        }
    }
}

// ---- pass 4: per-bucket LDS counting sort -> rowptr, csr, dinv-baked xs4 ----
// One block per 512-node bucket; its ~32KB edge slice is L2-resident across
// the two sweeps. Also emits xs4[n] = (x[n]*dinv, dinv): weight factorization
// w_e = dinv[s]*dinv[d] means csr needs ONLY src (no per-edge weight).
__global__ void bucket_sort(const unsigned* __restrict__ ebuf, const int* __restrict__ gbase,
                            const float* __restrict__ x,
                            int* __restrict__ rowptr, unsigned* __restrict__ csr,
                            float4* __restrict__ xs4, int N) {
    __shared__ int ldeg[512];
    __shared__ int loff[512];
    __shared__ int sd[NTPB];
    int t = threadIdx.x, b = blockIdx.x;
    int node0 = b << BSH;
    int beg = gbase[b], end = gbase[b + 1];
    ldeg[t] = 0; ldeg[t + 256] = 0;
    __syncthreads();
    for (int i = beg + t; i < end; i += NTPB)
        atomicAdd(&ldeg[ebuf[i] >> 17], 1);
    __syncthreads();
    int d0 = ldeg[2 * t], d1 = ldeg[2 * t + 1];
    int ps = d0 + d1;
    sd[t] = ps; __syncthreads();
    for (int s = 1; s < NTPB; s <<= 1) {
        int u = (t >= s) ? sd[t - s] : 0;
        __syncthreads();
        sd[t] += u;
        __syncthreads();
    }
    int ex = sd[t] - ps;
    loff[2 * t] = ex;
    loff[2 * t + 1] = ex + d0;
    __syncthreads();
    for (int i = t; i < 512; i += NTPB) {
        int node = node0 + i;
        if (node < N) {
            rowptr[node] = beg + loff[i];
            float dv = rsqrtf((float)(ldeg[i] + 1));
            xs4[node] = make_float4(x[3 * node] * dv, x[3 * node + 1] * dv,
                                    x[3 * node + 2] * dv, dv);
        } else if (node == N) {
            rowptr[N] = beg + loff[i];  // == E (all dst < N)
        }
    }
    __syncthreads();
    for (int i = beg + t; i < end; i += NTPB) {
        unsigned u = ebuf[i];
        int pos = beg + atomicAdd(&loff[u >> 17], 1);
        csr[pos] = u & 0x1FFFFu;
    }
}

// pre-pack W2 into bf16 B-fragments for mfma_f32_16x16x32_bf16
__global__ void bpack_kernel(const float* __restrict__ W2, __hip_bfloat16* __restrict__ Bp) {
    int idx = blockIdx.x * blockDim.x + threadIdx.x;  // 0..2047
    if (idx >= 2048) return;
    int frag = idx >> 6, lane = idx & 63;
    int nt = frag >> 2, c = frag & 3, quad = lane >> 4, m16 = lane & 15;
#pragma unroll
    for (int jj = 0; jj < 8; jj++) {
        int k = c * 32 + quad * 8 + jj;
        Bp[idx * 8 + jj] = __float2bfloat16(W2[k * H + nt * 16 + m16]);
    }
}

// layer-1 gather: aggx[d] = dinv[d] * (sum_e xs[s] + xs[d]); unweighted adds
__global__ void l1_gather(const float4* __restrict__ xs4,
                          const int* __restrict__ rowptr, const unsigned* __restrict__ csr,
                          float4* __restrict__ aggx4, int N) {
    int n = blockIdx.x * blockDim.x + threadIdx.x;
    if (n >= N) return;
    float4 xn = xs4[n];
    float a0 = xn.x, a1 = xn.y, a2 = xn.z;
    int beg = rowptr[n], end = rowptr[n + 1];
    int i = beg;
    for (; i + 4 <= end; i += 4) {
        float4 q0 = xs4[csr[i]];
        float4 q1 = xs4[csr[i + 1]];
        float4 q2 = xs4[csr[i + 2]];
        float4 q3 = xs4[csr[i + 3]];
        a0 += q0.x + q1.x + q2.x + q3.x;
        a1 += q0.y + q1.y + q2.y + q3.y;
        a2 += q0.z + q1.z + q2.z + q3.z;
    }
    for (; i < end; ++i) {
        float4 q = xs4[csr[i]];
        a0 += q.x; a1 += q.y; a2 += q.z;
    }
    float dv = xn.w;
    aggx4[n] = make_float4(a0 * dv, a1 * dv, a2 * dv, dv);
}

// FUSED layer-2 gather: agg1[d] = dinv[d]*(sum_e dinv[s]*h1[s] + dinv[d]*h1[d]),
// h1 = relu(aggx@W1+b1) recomputed on the fly from one 16B read/edge (p.w = dinv).
// NO launch_bounds (the (256,6) cap forced a 352MB scratch spill previously).
__global__ void l2_gather(
        const float4* __restrict__ aggx4,
        const int* __restrict__ rowptr, const unsigned* __restrict__ csr,
        const float* __restrict__ W1, const float* __restrict__ b1,
        __hip_bfloat16* __restrict__ agg1, int N) {
    int t = threadIdx.x;
    int l16 = t & 15;
    int node = blockIdx.x * 16 + (t >> 4);
    float wa[8], wb[8], wcc[8], bb[8];
#pragma unroll
    for (int j = 0; j < 8; j++) {
        int k = 8 * l16 + j;
        wa[j] = W1[k]; wb[j] = W1[H + k]; wcc[j] = W1[2 * H + k]; bb[j] = b1[k];
    }
    if (node >= N) return;
    float acc[8];
#pragma unroll
    for (int j = 0; j < 8; j++) acc[j] = 0.f;
    int beg = rowptr[node], end = rowptr[node + 1];
    for (int i = beg; i < end; i += 4) {
        int rem = end - i;
        // invalid slots get p = 0 -> p.w = 0 kills the (biased) relu term
        float4 p0 = aggx4[csr[i]];
        float4 p1 = (rem > 1) ? aggx4[csr[i + 1]] : make_float4(0.f, 0.f, 0.f, 0.f);
        float4 p2 = (rem > 2) ? aggx4[csr[i + 2]] : make_float4(0.f, 0.f, 0.f, 0.f);
        float4 p3 = (rem > 3) ? aggx4[csr[i + 3]] : make_float4(0.f, 0.f, 0.f, 0.f);
#pragma unroll
        for (int j = 0; j < 8; j++) {
            acc[j] += p0.w * fmaxf(p0.x * wa[j] + p0.y * wb[j] + p0.z * wcc[j] + bb[j], 0.f);
            acc[j] += p1.w * fmaxf(p1.x * wa[j] + p1.y * wb[j] + p1.z * wcc[j] + bb[j], 0.f);
            acc[j] += p2.w * fmaxf(p2.x * wa[j] + p2.y * wb[j] + p2.z * wcc[j] + bb[j], 0.f);
            acc[j] += p3.w * fmaxf(p3.x * wa[j] + p3.y * wb[j] + p3.z * wcc[j] + bb[j], 0.f);
        }
    }
    float4 ps = aggx4[node];
    float dv = ps.w;
#pragma unroll
    for (int j = 0; j < 8; j++)
        acc[j] += dv * fmaxf(ps.x * wa[j] + ps.y * wb[j] + ps.z * wcc[j] + bb[j], 0.f);
    short8 o;
#pragma unroll
    for (int j = 0; j < 8; j++) o[j] = f2bf(acc[j] * dv);
    *(short8*)(&agg1[(size_t)node * H + 8 * l16]) = o;
}

// Final MFMA: h2 = relu(agg1 @ W2 + b2); dot with Wc -> nodedot[row]. No atomics.
__global__ __launch_bounds__(NTPB, 4) void gemm_nodedot(
        const __hip_bfloat16* __restrict__ agg1, const __hip_bfloat16* __restrict__ Bp,
        const float* __restrict__ b2, const float* __restrict__ Wc,
        float* __restrict__ nodedot, int N) {
    __shared__ float sb2[H];
    __shared__ float swc[H];
    int t = threadIdx.x;
    if (t < H) { sb2[t] = b2[t]; swc[t] = Wc[t]; }
    __syncthreads();
    int wave = t >> 6, lane = t & 63;
    int quad = lane >> 4, m16 = lane & 15;
    int tile = blockIdx.x * 4 + wave;
    int rowbase = tile * 16;
    if (rowbase >= N) return;
    int m = rowbase + m16;
    const short8* as8 = (const short8*)agg1;
    short8 af[4];
    if (m < N) {
#pragma unroll
        for (int c = 0; c < 4; c++) af[c] = as8[(size_t)m * 16 + c * 4 + quad];
    } else {
#pragma unroll
        for (int c = 0; c < 4; c++) af[c] = (short8){0, 0, 0, 0, 0, 0, 0, 0};
    }
    const short8* bp = (const short8*)Bp;
    floatx4 acc[8];
#pragma unroll
    for (int nt = 0; nt < 8; nt++) acc[nt] = (floatx4){0.f, 0.f, 0.f, 0.f};
#pragma unroll
    for (int nt = 0; nt < 8; nt++) {
#pragma unroll
        for (int c = 0; c < 4; c++) {
            short8 bf = bp[(nt * 4 + c) * 64 + lane];
            acc[nt] = __builtin_amdgcn_mfma_f32_16x16x32_bf16(af[c], bf, acc[nt], 0, 0, 0);
        }
    }
    float dot0 = 0.f, dot1 = 0.f, dot2 = 0.f, dot3 = 0.f;
#pragma unroll
    for (int nt = 0; nt < 8; nt++) {
        int col = nt * 16 + m16;
        float bcol = sb2[col], wcol = swc[col];
        dot0 += fmaxf(acc[nt][0] + bcol, 0.f) * wcol;
        dot1 += fmaxf(acc[nt][1] + bcol, 0.f) * wcol;
        dot2 += fmaxf(acc[nt][2] + bcol, 0.f) * wcol;
        dot3 += fmaxf(acc[nt][3] + bcol, 0.f) * wcol;
    }
#pragma unroll
    for (int s = 1; s < 16; s <<= 1) {
        dot0 += __shfl_xor(dot0, s);
        dot1 += __shfl_xor(dot1, s);
        dot2 += __shfl_xor(dot2, s);
        dot3 += __shfl_xor(dot3, s);
    }
    if (m16 < 4) {
        int row = rowbase + quad * 4 + m16;
        if (row < N) {
            float d = (m16 == 0) ? dot0 : (m16 == 1) ? dot1 : (m16 == 2) ? dot2 : dot3;
            nodedot[row] = d;
        }
    }
}

// segmented mean-pool: LDS-privatized (batch sorted => ~12 graphs per chunk)
__global__ void pool_kernel(const float* __restrict__ nodedot, const int* __restrict__ batch,
                            float* __restrict__ gsum, int* __restrict__ gcnt, int N, int G) {
    extern __shared__ char sm[];
    float* ls = (float*)sm;
    int*   lc = (int*)(sm + (size_t)G * sizeof(float));
    int t = threadIdx.x;
    for (int g = t; g < G; g += blockDim.x) { ls[g] = 0.f; lc[g] = 0; }
    __syncthreads();
    int base = blockIdx.x * POOL_CHUNK;
    int endn = min(base + POOL_CHUNK, N);
    for (int n = base + t; n < endn; n += blockDim.x) {
        int g = batch[n];
        atomicAdd(&ls[g], nodedot[n]);
        atomicAdd(&lc[g], 1);
    }
    __syncthreads();
    for (int g = t; g < G; g += blockDim.x) {
        if (lc[g] != 0) {
            atomAddF(&gsum[g], ls[g]);
            atomicAdd(&gcnt[g], lc[g]);
        }
    }
}

__global__ void out_kernel(const float* __restrict__ gsum, const int* __restrict__ gcnt,
                           const float* __restrict__ bc, float* __restrict__ out, int G) {
    int g = blockIdx.x * blockDim.x + threadIdx.x;
    if (g >= G) return;
    float c = fmaxf((float)gcnt[g], 1.f);
    float logit = gsum[g] / c + bc[0];
    out[g] = 1.f / (1.f + expf(-logit));
}

extern "C" void kernel_launch(void* const* d_in, const int* in_sizes, int n_in,
                              void* d_out, int out_size, void* d_ws, size_t ws_size,
                              hipStream_t stream) {
    const float* x     = (const float*)d_in[0];
    const int*   ei    = (const int*)d_in[1];
    const int*   batch = (const int*)d_in[2];
    const float* W1    = (const float*)d_in[3];
    const float* b1    = (const float*)d_in[4];
    const float* W2    = (const float*)d_in[5];
    const float* b2    = (const float*)d_in[6];
    const float* Wc    = (const float*)d_in[7];
    const float* bc    = (const float*)d_in[8];
    float* out = (float*)d_out;

    int N = in_sizes[2];
    int E = in_sizes[1] / 2;
    int G = out_size;

    char* ws = (char*)d_ws;
    size_t off = 0;
    auto alloc = [&](size_t bytes) {
        void* p = ws + off;
        off += (bytes + 255) & ~(size_t)255;
        return p;
    };
    __hip_bfloat16* agg1 = (__hip_bfloat16*)alloc((size_t)N * H * sizeof(__hip_bfloat16));
    float4* xs4   = (float4*)alloc((size_t)N * sizeof(float4));
    float4* aggx4 = (float4*)alloc((size_t)N * sizeof(float4));
    float* nodedot= (float*)alloc((size_t)N * sizeof(float));
    // zeroed block: gsum/gcnt/ghist contiguous -> single memset
    float* gsum   = (float*)alloc((size_t)G * sizeof(float));
    int*   gcnt   = (int*)  alloc((size_t)G * sizeof(int));
    int*   ghist  = (int*)  alloc((size_t)NBKT * sizeof(int));
    char*  zero_end = ws + off;
    int*   gbase  = (int*)  alloc((size_t)(NBKT + 1) * sizeof(int));
    int*   gcursor= (int*)  alloc((size_t)NBKT * sizeof(int));
    int*   rowptr = (int*)  alloc((size_t)(N + 1) * sizeof(int));
    unsigned* csr = (unsigned*)alloc((size_t)E * sizeof(unsigned));
    unsigned* ebuf= (unsigned*)alloc((size_t)E * sizeof(unsigned));
    __hip_bfloat16* Bp = (__hip_bfloat16*)alloc((size_t)H * H * sizeof(__hip_bfloat16));

    (void)hipMemsetAsync(gsum, 0, (size_t)(zero_end - (char*)gsum), stream);

    int EB = (E + EPB - 1) / EPB;
    hist_kernel<<<EB, NTPB, 0, stream>>>(ei, E, ghist);
    scan_buckets<<<1, NBKT, 0, stream>>>(ghist, gbase, gcursor);
    partition_kernel<<<EB, NTPB, 0, stream>>>(ei, E, gcursor, ebuf);
    {
        int nbs = (N >> BSH) + 1;
        bucket_sort<<<nbs, NTPB, 0, stream>>>(ebuf, gbase, x, rowptr, csr, xs4, N);
    }

    bpack_kernel<<<8, NTPB, 0, stream>>>(W2, Bp);

    l1_gather<<<(N + NTPB - 1) / NTPB, NTPB, 0, stream>>>(xs4, rowptr, csr, aggx4, N);

    l2_gather<<<(N + 15) / 16, NTPB, 0, stream>>>(aggx4, rowptr, csr, W1, b1, agg1, N);

    {
        int ntiles = (N + 15) / 16;
        gemm_nodedot<<<(ntiles + 3) / 4, NTPB, 0, stream>>>(agg1, Bp, b2, Wc, nodedot, N);
    }

    {
        int pblocks = (N + POOL_CHUNK - 1) / POOL_CHUNK;
        size_t smem = (size_t)G * (sizeof(float) + sizeof(int));
        pool_kernel<<<pblocks, NTPB, smem, stream>>>(nodedot, batch, gsum, gcnt, N, G);
    }

    out_kernel<<<(G + NTPB - 1) / NTPB, NTPB, 0, stream>>>(gsum, gcnt, bc, out, G);
}

// Round 5
// 230.653 us; speedup vs baseline: 2.3697x; 1.0697x over previous
//
#include <hip/hip_runtime.h>
#include <hip/hip_bf16.h>
#include <math.h>

#define H 128
#define NTPB 256
#define NBKT 256      // dst buckets, 512 nodes each
#define BSH 9
#define BMSK 511
#define EPB 8192      // edges per partition/hist block
#define POOL_CHUNK 2048

typedef __attribute__((ext_vector_type(8))) short short8;
typedef __attribute__((ext_vector_type(4))) float floatx4;
typedef __attribute__((ext_vector_type(2))) float f2v;

__device__ __forceinline__ void atomAddF(float* p, float v) {
    __hip_atomic_fetch_add(p, v, __ATOMIC_RELAXED, __HIP_MEMORY_SCOPE_AGENT);
}

__device__ __forceinline__ short f2bf(float v) {
    __hip_bfloat16 b = __float2bfloat16(v);
    return __builtin_bit_cast(short, b);
}

__device__ __forceinline__ f2v splat2(float v) { return (f2v){v, v}; }

// ---- CSR build, pass 1: per-bucket edge histogram (bucket = dst>>9) ----
__global__ void hist_kernel(const int* __restrict__ ei, int E, int* __restrict__ ghist) {
    __shared__ int lh[NBKT];
    int t = threadIdx.x;
    lh[t] = 0;
    __syncthreads();
    int base = blockIdx.x * EPB;
#pragma unroll
    for (int k = 0; k < EPB / NTPB; k++) {
        int e = base + k * NTPB + t;
        if (e < E) atomicAdd(&lh[((unsigned)ei[E + e]) >> BSH], 1);
    }
    __syncthreads();
    if (lh[t]) atomicAdd(&ghist[t], lh[t]);
}

// ---- pass 2: scan bucket counts -> gbase[257]; init gcursor ----
__global__ void scan_buckets(const int* __restrict__ ghist, int* __restrict__ gbase,
                             int* __restrict__ gcursor) {
    __shared__ int sd[NBKT];
    int t = threadIdx.x;
    int v = ghist[t];
    sd[t] = v; __syncthreads();
    for (int s = 1; s < NBKT; s <<= 1) {
        int u = (t >= s) ? sd[t - s] : 0;
        __syncthreads();
        sd[t] += u;
        __syncthreads();
    }
    int ex = sd[t] - v;
    gbase[t] = ex;
    gcursor[t] = ex;
    if (t == NBKT - 1) gbase[NBKT] = sd[t];
}

// ---- pass 3: partition edges into bucket-contiguous ebuf ----
__global__ void partition_kernel(const int* __restrict__ ei, int E,
                                 int* __restrict__ gcursor, unsigned* __restrict__ ebuf) {
    __shared__ int lcur[NBKT];
    __shared__ int lbase[NBKT];
    int t = threadIdx.x;
    lcur[t] = 0;
    __syncthreads();
    int base = blockIdx.x * EPB;
    unsigned short rk[EPB / NTPB];
#pragma unroll
    for (int k = 0; k < EPB / NTPB; k++) {
        int e = base + k * NTPB + t;
        rk[k] = 0;
        if (e < E) rk[k] = (unsigned short)atomicAdd(&lcur[((unsigned)ei[E + e]) >> BSH], 1);
    }
    __syncthreads();
    lbase[t] = atomicAdd(&gcursor[t], lcur[t]);
    __syncthreads();
#pragma unroll
    for (int k = 0; k < EPB / NTPB; k++) {
        int e = base + k * NTPB + t;
        if (e < E) {
            unsigned d = (unsigned)ei[E + e];
            unsigned s = (unsigned)ei[e];
            ebuf[lbase[d >> BSH] + rk[k]] = ((d & BMSK) << 17) | s;
        }
    }
}

// ---- pass 4: per-bucket LDS counting sort -> rowptr, csr, dinv-baked xs4 ----
__global__ void bucket_sort(const unsigned* __restrict__ ebuf, const int* __restrict__ gbase,
                            const float* __restrict__ x,
                            int* __restrict__ rowptr, unsigned* __restrict__ csr,
                            float4* __restrict__ xs4, int N) {
    __shared__ int ldeg[512];
    __shared__ int loff[512];
    __shared__ int sd[NTPB];
    int t = threadIdx.x, b = blockIdx.x;
    int node0 = b << BSH;
    int beg = gbase[b], end = gbase[b + 1];
    ldeg[t] = 0; ldeg[t + 256] = 0;
    __syncthreads();
    for (int i = beg + t; i < end; i += NTPB)
        atomicAdd(&ldeg[ebuf[i] >> 17], 1);
    __syncthreads();
    int d0 = ldeg[2 * t], d1 = ldeg[2 * t + 1];
    int ps = d0 + d1;
    sd[t] = ps; __syncthreads();
    for (int s = 1; s < NTPB; s <<= 1) {
        int u = (t >= s) ? sd[t - s] : 0;
        __syncthreads();
        sd[t] += u;
        __syncthreads();
    }
    int ex = sd[t] - ps;
    loff[2 * t] = ex;
    loff[2 * t + 1] = ex + d0;
    __syncthreads();
    for (int i = t; i < 512; i += NTPB) {
        int node = node0 + i;
        if (node < N) {
            rowptr[node] = beg + loff[i];
            float dv = rsqrtf((float)(ldeg[i] + 1));
            xs4[node] = make_float4(x[3 * node] * dv, x[3 * node + 1] * dv,
                                    x[3 * node + 2] * dv, dv);
        } else if (node == N) {
            rowptr[N] = beg + loff[i];  // == E (all dst < N)
        }
    }
    __syncthreads();
    for (int i = beg + t; i < end; i += NTPB) {
        unsigned u = ebuf[i];
        int pos = beg + atomicAdd(&loff[u >> 17], 1);
        csr[pos] = u & 0x1FFFFu;
    }
}

// pre-pack W2 into bf16 B-fragments for mfma_f32_16x16x32_bf16
__global__ void bpack_kernel(const float* __restrict__ W2, __hip_bfloat16* __restrict__ Bp) {
    int idx = blockIdx.x * blockDim.x + threadIdx.x;  // 0..2047
    if (idx >= 2048) return;
    int frag = idx >> 6, lane = idx & 63;
    int nt = frag >> 2, c = frag & 3, quad = lane >> 4, m16 = lane & 15;
#pragma unroll
    for (int jj = 0; jj < 8; jj++) {
        int k = c * 32 + quad * 8 + jj;
        Bp[idx * 8 + jj] = __float2bfloat16(W2[k * H + nt * 16 + m16]);
    }
}

// layer-1 gather: aggx[d] = dinv[d] * (sum_e xs[s] + xs[d]); unweighted adds
__global__ void l1_gather(const float4* __restrict__ xs4,
                          const int* __restrict__ rowptr, const unsigned* __restrict__ csr,
                          float4* __restrict__ aggx4, int N) {
    int n = blockIdx.x * blockDim.x + threadIdx.x;
    if (n >= N) return;
    float4 xn = xs4[n];
    float a0 = xn.x, a1 = xn.y, a2 = xn.z;
    int beg = rowptr[n], end = rowptr[n + 1];
    int i = beg;
    for (; i + 4 <= end; i += 4) {
        float4 q0 = xs4[csr[i]];
        float4 q1 = xs4[csr[i + 1]];
        float4 q2 = xs4[csr[i + 2]];
        float4 q3 = xs4[csr[i + 3]];
        a0 += q0.x + q1.x + q2.x + q3.x;
        a1 += q0.y + q1.y + q2.y + q3.y;
        a2 += q0.z + q1.z + q2.z + q3.z;
    }
    for (; i < end; ++i) {
        float4 q = xs4[csr[i]];
        a0 += q.x; a1 += q.y; a2 += q.z;
    }
    float dv = xn.w;
    aggx4[n] = make_float4(a0 * dv, a1 * dv, a2 * dv, dv);
}

// per-edge layer-2 work: z = relu(aggx[s]@W1 + b1) on this lane's 2 dims,
// acc += dinv_s * z.  float2 fma chains -> v_pk_fma_f32 candidates.
__device__ __forceinline__ void edge_acc(const float4 p, const f2v wa, const f2v wb,
                                         const f2v wc, const f2v bb, f2v& acc) {
    f2v z = __builtin_elementwise_fma(splat2(p.x), wa, bb);
    z = __builtin_elementwise_fma(splat2(p.y), wb, z);
    z = __builtin_elementwise_fma(splat2(p.z), wc, z);
    z = __builtin_elementwise_max(z, (f2v){0.f, 0.f});
    acc = __builtin_elementwise_fma(splat2(p.w), z, acc);
}

// FUSED layer-2 gather, ONE NODE PER 64-LANE WAVE (2 dims/lane as float2).
// node is readfirstlane'd -> rowptr/csr/aggx4 addresses are wave-uniform
// (scalar pipe), zero divergence, no in-loop tail conditionals (clean 4-edge
// unroll + scalar tail).
__global__ void l2_gather(
        const float4* __restrict__ aggx4,
        const int* __restrict__ rowptr, const unsigned* __restrict__ csr,
        const float* __restrict__ W1, const float* __restrict__ b1,
        __hip_bfloat16* __restrict__ agg1, int N) {
    int t = threadIdx.x;
    int lane = t & 63;
    int node = __builtin_amdgcn_readfirstlane(blockIdx.x * 4 + (t >> 6));
    if (node >= N) return;
    int k0 = 2 * lane;  // this lane's output dims {k0, k0+1}
    f2v wa = *(const f2v*)&W1[k0];
    f2v wb = *(const f2v*)&W1[H + k0];
    f2v wc = *(const f2v*)&W1[2 * H + k0];
    f2v bb = *(const f2v*)&b1[k0];
    f2v acc = (f2v){0.f, 0.f};
    int beg = rowptr[node], end = rowptr[node + 1];
    int i = beg;
    for (; i + 4 <= end; i += 4) {
        unsigned s0 = csr[i], s1 = csr[i + 1], s2 = csr[i + 2], s3 = csr[i + 3];
        float4 p0 = aggx4[s0];
        float4 p1 = aggx4[s1];
        float4 p2 = aggx4[s2];
        float4 p3 = aggx4[s3];
        edge_acc(p0, wa, wb, wc, bb, acc);
        edge_acc(p1, wa, wb, wc, bb, acc);
        edge_acc(p2, wa, wb, wc, bb, acc);
        edge_acc(p3, wa, wb, wc, bb, acc);
    }
    for (; i < end; ++i) {
        float4 p = aggx4[csr[i]];
        edge_acc(p, wa, wb, wc, bb, acc);
    }
    // self-loop: acc += dv * relu(...); then whole row scaled by dv
    float4 ps = aggx4[node];
    edge_acc(ps, wa, wb, wc, bb, acc);
    float dv = ps.w;
    f2v r = acc * splat2(dv);
    unsigned packed = ((unsigned)(unsigned short)f2bf(r.x)) |
                      ((unsigned)(unsigned short)f2bf(r.y) << 16);
    ((unsigned*)agg1)[(size_t)node * (H / 2) + lane] = packed;
}

// Final MFMA: h2 = relu(agg1 @ W2 + b2); dot with Wc -> nodedot[row]. No atomics.
__global__ __launch_bounds__(NTPB, 4) void gemm_nodedot(
        const __hip_bfloat16* __restrict__ agg1, const __hip_bfloat16* __restrict__ Bp,
        const float* __restrict__ b2, const float* __restrict__ Wc,
        float* __restrict__ nodedot, int N) {
    __shared__ float sb2[H];
    __shared__ float swc[H];
    int t = threadIdx.x;
    if (t < H) { sb2[t] = b2[t]; swc[t] = Wc[t]; }
    __syncthreads();
    int wave = t >> 6, lane = t & 63;
    int quad = lane >> 4, m16 = lane & 15;
    int tile = blockIdx.x * 4 + wave;
    int rowbase = tile * 16;
    if (rowbase >= N) return;
    int m = rowbase + m16;
    const short8* as8 = (const short8*)agg1;
    short8 af[4];
    if (m < N) {
#pragma unroll
        for (int c = 0; c < 4; c++) af[c] = as8[(size_t)m * 16 + c * 4 + quad];
    } else {
#pragma unroll
        for (int c = 0; c < 4; c++) af[c] = (short8){0, 0, 0, 0, 0, 0, 0, 0};
    }
    const short8* bp = (const short8*)Bp;
    floatx4 acc[8];
#pragma unroll
    for (int nt = 0; nt < 8; nt++) acc[nt] = (floatx4){0.f, 0.f, 0.f, 0.f};
#pragma unroll
    for (int nt = 0; nt < 8; nt++) {
#pragma unroll
        for (int c = 0; c < 4; c++) {
            short8 bf = bp[(nt * 4 + c) * 64 + lane];
            acc[nt] = __builtin_amdgcn_mfma_f32_16x16x32_bf16(af[c], bf, acc[nt], 0, 0, 0);
        }
    }
    float dot0 = 0.f, dot1 = 0.f, dot2 = 0.f, dot3 = 0.f;
#pragma unroll
    for (int nt = 0; nt < 8; nt++) {
        int col = nt * 16 + m16;
        float bcol = sb2[col], wcol = swc[col];
        dot0 += fmaxf(acc[nt][0] + bcol, 0.f) * wcol;
        dot1 += fmaxf(acc[nt][1] + bcol, 0.f) * wcol;
        dot2 += fmaxf(acc[nt][2] + bcol, 0.f) * wcol;
        dot3 += fmaxf(acc[nt][3] + bcol, 0.f) * wcol;
    }
#pragma unroll
    for (int s = 1; s < 16; s <<= 1) {
        dot0 += __shfl_xor(dot0, s);
        dot1 += __shfl_xor(dot1, s);
        dot2 += __shfl_xor(dot2, s);
        dot3 += __shfl_xor(dot3, s);
    }
    if (m16 < 4) {
        int row = rowbase + quad * 4 + m16;
        if (row < N) {
            float d = (m16 == 0) ? dot0 : (m16 == 1) ? dot1 : (m16 == 2) ? dot2 : dot3;
            nodedot[row] = d;
        }
    }
}

// segmented mean-pool: LDS-privatized (batch sorted => ~12 graphs per chunk)
__global__ void pool_kernel(const float* __restrict__ nodedot, const int* __restrict__ batch,
                            float* __restrict__ gsum, int* __restrict__ gcnt, int N, int G) {
    extern __shared__ char sm[];
    float* ls = (float*)sm;
    int*   lc = (int*)(sm + (size_t)G * sizeof(float));
    int t = threadIdx.x;
    for (int g = t; g < G; g += blockDim.x) { ls[g] = 0.f; lc[g] = 0; }
    __syncthreads();
    int base = blockIdx.x * POOL_CHUNK;
    int endn = min(base + POOL_CHUNK, N);
    for (int n = base + t; n < endn; n += blockDim.x) {
        int g = batch[n];
        atomicAdd(&ls[g], nodedot[n]);
        atomicAdd(&lc[g], 1);
    }
    __syncthreads();
    for (int g = t; g < G; g += blockDim.x) {
        if (lc[g] != 0) {
            atomAddF(&gsum[g], ls[g]);
            atomicAdd(&gcnt[g], lc[g]);
        }
    }
}

__global__ void out_kernel(const float* __restrict__ gsum, const int* __restrict__ gcnt,
                           const float* __restrict__ bc, float* __restrict__ out, int G) {
    int g = blockIdx.x * blockDim.x + threadIdx.x;
    if (g >= G) return;
    float c = fmaxf((float)gcnt[g], 1.f);
    float logit = gsum[g] / c + bc[0];
    out[g] = 1.f / (1.f + expf(-logit));
}

extern "C" void kernel_launch(void* const* d_in, const int* in_sizes, int n_in,
                              void* d_out, int out_size, void* d_ws, size_t ws_size,
                              hipStream_t stream) {
    const float* x     = (const float*)d_in[0];
    const int*   ei    = (const int*)d_in[1];
    const int*   batch = (const int*)d_in[2];
    const float* W1    = (const float*)d_in[3];
    const float* b1    = (const float*)d_in[4];
    const float* W2    = (const float*)d_in[5];
    const float* b2    = (const float*)d_in[6];
    const float* Wc    = (const float*)d_in[7];
    const float* bc    = (const float*)d_in[8];
    float* out = (float*)d_out;

    int N = in_sizes[2];
    int E = in_sizes[1] / 2;
    int G = out_size;

    char* ws = (char*)d_ws;
    size_t off = 0;
    auto alloc = [&](size_t bytes) {
        void* p = ws + off;
        off += (bytes + 255) & ~(size_t)255;
        return p;
    };
    __hip_bfloat16* agg1 = (__hip_bfloat16*)alloc((size_t)N * H * sizeof(__hip_bfloat16));
    float4* xs4   = (float4*)alloc((size_t)N * sizeof(float4));
    float4* aggx4 = (float4*)alloc((size_t)N * sizeof(float4));
    float* nodedot= (float*)alloc((size_t)N * sizeof(float));
    // zeroed block: gsum/gcnt/ghist contiguous -> single memset
    float* gsum   = (float*)alloc((size_t)G * sizeof(float));
    int*   gcnt   = (int*)  alloc((size_t)G * sizeof(int));
    int*   ghist  = (int*)  alloc((size_t)NBKT * sizeof(int));
    char*  zero_end = ws + off;
    int*   gbase  = (int*)  alloc((size_t)(NBKT + 1) * sizeof(int));
    int*   gcursor= (int*)  alloc((size_t)NBKT * sizeof(int));
    int*   rowptr = (int*)  alloc((size_t)(N + 1) * sizeof(int));
    unsigned* csr = (unsigned*)alloc((size_t)E * sizeof(unsigned));
    unsigned* ebuf= (unsigned*)alloc((size_t)E * sizeof(unsigned));
    __hip_bfloat16* Bp = (__hip_bfloat16*)alloc((size_t)H * H * sizeof(__hip_bfloat16));

    (void)hipMemsetAsync(gsum, 0, (size_t)(zero_end - (char*)gsum), stream);

    int EB = (E + EPB - 1) / EPB;
    hist_kernel<<<EB, NTPB, 0, stream>>>(ei, E, ghist);
    scan_buckets<<<1, NBKT, 0, stream>>>(ghist, gbase, gcursor);
    partition_kernel<<<EB, NTPB, 0, stream>>>(ei, E, gcursor, ebuf);
    {
        int nbs = (N >> BSH) + 1;
        bucket_sort<<<nbs, NTPB, 0, stream>>>(ebuf, gbase, x, rowptr, csr, xs4, N);
    }

    bpack_kernel<<<8, NTPB, 0, stream>>>(W2, Bp);

    l1_gather<<<(N + NTPB - 1) / NTPB, NTPB, 0, stream>>>(xs4, rowptr, csr, aggx4, N);

    l2_gather<<<(N + 3) / 4, NTPB, 0, stream>>>(aggx4, rowptr, csr, W1, b1, agg1, N);

    {
        int ntiles = (N + 15) / 16;
        gemm_nodedot<<<(ntiles + 3) / 4, NTPB, 0, stream>>>(agg1, Bp, b2, Wc, nodedot, N);
    }

    {
        int pblocks = (N + POOL_CHUNK - 1) / POOL_CHUNK;
        size_t smem = (size_t)G * (sizeof(float) + sizeof(int));
        pool_kernel<<<pblocks, NTPB, smem, stream>>>(nodedot, batch, gsum, gcnt, N, G);
    }

    out_kernel<<<(G + NTPB - 1) / NTPB, NTPB, 0, stream>>>(gsum, gcnt, bc, out, G);
}